// Round 13
// baseline (712.554 us; speedup 1.0000x reference)
//
#include <hip/hip_runtime.h>

#define DD 48
#define HWQ 2304              // 48*48
#define QQ 110592             // 48^3
#define NK 7

typedef _Float16 f16x8 __attribute__((ext_vector_type(8)));
typedef float f32x16 __attribute__((ext_vector_type(16)));
union U4H8 { uint4 u; f16x8 h; };
union U2H4 { uint2 u; _Float16 h[4]; };

__device__ __forceinline__ void load16_lds(const void* g, void* l) {
    __builtin_amdgcn_global_load_lds(
        (const __attribute__((address_space(1))) unsigned int*)g,
        (__attribute__((address_space(3))) unsigned int*)l, 16, 0, 0);
}

// ---- x (f32 [b][32][z][y][x]) -> PADDED hi/lo fp16 [b][z][50y'][4kg][50x'][8ch], zero borders ----
__global__ __launch_bounds__(256) void transpose_x(const float* __restrict__ x,
                                                   _Float16* __restrict__ xh,
                                                   _Float16* __restrict__ xl) {
    const int idx = blockIdx.x * 256 + threadIdx.x;   // 0..2499
    if (idx >= 2500) return;
    const int z = blockIdx.y, b = blockIdx.z;
    const int yp = idx / 50, xp = idx % 50;
    const bool interior = (yp >= 1 && yp <= 48 && xp >= 1 && xp <= 48);
    for (int kg = 0; kg < 4; kg++) {
        U4H8 hi, lo;
        #pragma unroll
        for (int j = 0; j < 8; j++) { hi.h[j] = (_Float16)0.f; lo.h[j] = (_Float16)0.f; }
        if (interior) {
            #pragma unroll
            for (int j = 0; j < 8; j++) {
                float v = x[(((size_t)b * 32 + kg * 8 + j) * DD + z) * HWQ + (yp - 1) * 48 + (xp - 1)];
                _Float16 h = (_Float16)v;
                hi.h[j] = h;
                lo.h[j] = (_Float16)((v - (float)h) * 2048.0f);
            }
        }
        size_t seg = ((((size_t)b * DD + z) * 50 + yp) * 4 + kg) * 50 + xp;
        ((uint4*)xh)[seg] = hi.u;
        ((uint4*)xl)[seg] = lo.u;
    }
}

// ---------------- A-fragment prepack, both convs in one kernel ----------------
__global__ __launch_bounds__(256) void prep_w(const float* __restrict__ w_in,
                                              const float* __restrict__ w_out,
                                              uint4* __restrict__ Wp1, uint4* __restrict__ Wp2) {
    int idx = blockIdx.x * 256 + threadIdx.x;
    const int n1 = 27 * 6 * 2 * 64;   // 20736
    const int n2 = 27 * 4 * 2 * 64;   // 13824
    if (idx < n1) {
        int l = idx & 63; int r = idx >> 6; int oh = r & 1; r >>= 1; int ks = r % 6; int tap = r / 6;
        int o = oh * 32 + (l & 31);
        U4H8 a;
        #pragma unroll
        for (int j = 0; j < 8; j++) {
            int ip = ks * 16 + (l >> 5) * 8 + j;
            _Float16 v;
            if (ip < 32) {
                v = (_Float16)w_in[(o * 32 + ip) * 27 + tap];
            } else if (ip < 64) {
                float w = w_in[(o * 32 + ip - 32) * 27 + tap];
                _Float16 h = (_Float16)w;
                v = (_Float16)((w - (float)h) * 2048.0f);
            } else {
                v = (_Float16)w_in[(o * 32 + ip - 64) * 27 + tap];
            }
            a.h[j] = v;
        }
        Wp1[idx] = a.u;
    } else if (idx < n1 + n2) {
        int j2 = idx - n1;
        int l = j2 & 63; int r = j2 >> 6; int oh = r & 1; r >>= 1; int ks = r % 4; int tap = r / 4;
        int o = oh * 32 + (l & 31);
        U4H8 a;
        #pragma unroll
        for (int j = 0; j < 8; j++) {
            int ip = ks * 16 + (l >> 5) * 8 + j;
            a.h[j] = (_Float16)w_out[(o * 64 + ip) * 27 + tap];
        }
        Wp2[j2] = a.u;
    }
}

// ---- MFMA conv v3 (verified): dz double-buffered staging + XCD-swizzled 1D grid ----
template<int KP, int CINP>
__global__ __launch_bounds__(256) void conv_mfma(const _Float16* __restrict__ src0,
                                                 const _Float16* __restrict__ src1,
                                                 const uint4* __restrict__ Wp,
                                                 float* __restrict__ out) {
    constexpr bool SPLIT = (KP != CINP);       // conv1: 96 vs 32
    constexpr int KSTEPS = KP / 16;
    constexpr int KG = CINP / 8;               // 4 (conv1) or 8 (conv2)
    constexpr int SEGS = 6 * KG * 50;          // per region: 1200 or 2400
    constexpr int YSTRIDE = KG * 800;          // bytes per y' row
    __shared__ char lds[2 * 38400];

    const int lin = blockIdx.x;
    const int swz = (lin & 7) * 144 + (lin >> 3);
    const int b = swz / 576;
    const int rem = swz % 576;
    const int ytile = rem / 48;
    const int z = rem % 48;

    const int tid = threadIdx.x;
    const int l = tid & 63;
    const int wv = tid >> 6;
    const int ohalf = wv & 1, qhalf = wv >> 1;
    const int hi5 = l >> 5;

    int fbase[3];
    #pragma unroll
    for (int f = 0; f < 3; f++) {
        int q = qhalf * 96 + f * 32 + (l & 31);
        fbase[f] = (q / 48) * YSTRIDE + (q % 48) * 16;
    }

    f32x16 accH[3], accL[3];
    #pragma unroll
    for (int f = 0; f < 3; f++)
        #pragma unroll
        for (int rr = 0; rr < 16; rr++) { accH[f][rr] = 0.f; if (SPLIT) accL[f][rr] = 0.f; }

    auto stage = [&](int dz, int bufsel) {
        int zin = z + dz - 1;
        zin = zin < 0 ? 0 : (zin >= DD ? DD - 1 : zin);   // clamp; edge data unused
        const size_t seg0 = (((size_t)b * DD + zin) * 50 + ytile * 4) * (size_t)(KG * 50);
        char* base = lds + bufsel * 38400;
        const _Float16* sA = src0 + seg0 * 8;
        for (int i = tid; i < SEGS; i += 256)
            load16_lds(sA + (size_t)i * 8, base + i * 16);
        if (SPLIT) {
            const _Float16* sB = src1 + seg0 * 8;
            for (int i = tid; i < SEGS; i += 256)
                load16_lds(sB + (size_t)i * 8, base + 19200 + i * 16);
        }
    };

    stage(0, 0);
    __syncthreads();
    for (int dz = 0; dz < 3; dz++) {
        if (dz < 2) stage(dz + 1, (dz + 1) & 1);      // prefetch next plane (other buffer)
        const int zin = z + dz - 1;
        if (zin >= 0 && zin < DD) {
            const char* base = lds + (dz & 1) * 38400;
            for (int dy = 0; dy < 3; dy++) {
                for (int dx = 0; dx < 3; dx++) {
                    const int tap = (dz * 3 + dy) * 3 + dx;
                    const uint4* wp = Wp + ((size_t)(tap * KSTEPS) * 2 + ohalf) * 64 + l;
                    #pragma unroll
                    for (int ks = 0; ks < KSTEPS; ks++) {
                        U4H8 a; a.u = wp[ks * 128];
                        const int kgp = ks * 2;
                        const int pl0 = SPLIT ? ((kgp < CINP / 4) ? (kgp & (CINP / 8 - 1)) : (kgp - CINP / 8))
                                              : kgp;
                        const int plane = pl0 + hi5;
                        const int grp = SPLIT ? (plane >> 2) : 0;
                        const int kg  = SPLIT ? (plane & 3) : plane;
                        const int C = grp * 19200 + kg * 800 + dy * YSTRIDE + dx * 16;
                        #pragma unroll
                        for (int f = 0; f < 3; f++) {
                            f16x8 bf = *(const f16x8*)(base + fbase[f] + C);
                            if constexpr (SPLIT) {
                                if (ks < CINP / 16)
                                    accH[f] = __builtin_amdgcn_mfma_f32_32x32x16_f16(a.h, bf, accH[f], 0, 0, 0);
                                else
                                    accL[f] = __builtin_amdgcn_mfma_f32_32x32x16_f16(a.h, bf, accL[f], 0, 0, 0);
                            } else {
                                accH[f] = __builtin_amdgcn_mfma_f32_32x32x16_f16(a.h, bf, accH[f], 0, 0, 0);
                            }
                        }
                    }
                }
            }
        }
        __syncthreads();
    }

    const size_t obase = (((size_t)b * 64 + ohalf * 32) * DD + z) * HWQ + (size_t)ytile * 192;
    #pragma unroll
    for (int f = 0; f < 3; f++) {
        int q = qhalf * 96 + f * 32 + (l & 31);
        #pragma unroll
        for (int rr = 0; rr < 16; rr++) {
            int row = (rr & 3) + 8 * (rr >> 2) + 4 * (l >> 5);
            float val = accH[f][rr];
            if constexpr (SPLIT) val += accL[f][rr] * (1.0f / 2048.0f);
            out[obase + (size_t)row * QQ + q] = val;
        }
    }
}

// ---------------- InstanceNorm: sliced partial stats + merge ----------------
__global__ __launch_bounds__(256) void stats_part(const float* __restrict__ x, float2* __restrict__ pp) {
    __shared__ float ssum[256], ssq[256];
    const int s = blockIdx.x, bc = blockIdx.y;
    const float4* p = reinterpret_cast<const float4*>(x + (size_t)bc * QQ) + s * (QQ / 32);
    float sm = 0.f, q2 = 0.f;
    for (int i = threadIdx.x; i < QQ / 32; i += 256) {
        float4 v = p[i];
        sm += v.x + v.y + v.z + v.w;
        q2 += v.x * v.x + v.y * v.y + v.z * v.z + v.w * v.w;
    }
    ssum[threadIdx.x] = sm; ssq[threadIdx.x] = q2;
    __syncthreads();
    for (int off = 128; off > 0; off >>= 1) {
        if (threadIdx.x < off) {
            ssum[threadIdx.x] += ssum[threadIdx.x + off];
            ssq[threadIdx.x]  += ssq[threadIdx.x + off];
        }
        __syncthreads();
    }
    if (threadIdx.x == 0) pp[bc * 8 + s] = make_float2(ssum[0], ssq[0]);
}

__global__ __launch_bounds__(128) void stats_merge(const float2* __restrict__ pp, float2* __restrict__ st) {
    int bc = threadIdx.x;
    float sm = 0.f, q2 = 0.f;
    for (int i = 0; i < 8; i++) { float2 v = pp[bc * 8 + i]; sm += v.x; q2 += v.y; }
    float mean = sm / (float)QQ;
    float var = q2 / (float)QQ - mean * mean;
    st[bc] = make_float2(mean, rsqrtf(var + 1e-5f));
}

__global__ __launch_bounds__(256) void inorm_apply(const float* __restrict__ x, const float2* __restrict__ st,
                                                   float* __restrict__ y) {
    const int bc = blockIdx.y;
    float2 mv = st[bc];
    int idx = blockIdx.x * 256 + threadIdx.x;
    float4 v = reinterpret_cast<const float4*>(x + (size_t)bc * QQ)[idx];
    v.x = fmaxf((v.x - mv.x) * mv.y, 0.f);
    v.y = fmaxf((v.y - mv.x) * mv.y, 0.f);
    v.z = fmaxf((v.z - mv.x) * mv.y, 0.f);
    v.w = fmaxf((v.w - mv.x) * mv.y, 0.f);
    reinterpret_cast<float4*>(y + (size_t)bc * QQ)[idx] = v;
}

// ---- zero only the halo segments of padded oT (interior fully written by scatter_mfma) ----
__global__ __launch_bounds__(256) void zero_borders(uint4* __restrict__ oT) {
    int idx = blockIdx.x * 256 + threadIdx.x;
    if (idx >= 2 * 48 * 8 * 196) return;
    int pos = idx % 196; int r = idx / 196;
    int kg = r % 8; r /= 8; int z = r % 48; int b = r / 48;
    int yp, xp;
    if (pos < 50)       { yp = 0;  xp = pos; }
    else if (pos < 100) { yp = 49; xp = pos - 50; }
    else { int e = pos - 100; yp = 1 + (e >> 1); xp = (e & 1) ? 49 : 0; }
    oT[((((size_t)b * 48 + z) * 50 + yp) * 8 + kg) * 50 + xp] = make_uint4(0, 0, 0, 0);
}

// ---------------- k-means on precomputed x1 (f32) ----------------
// 256-pt blocks, grid (432, 2): R10's fill pattern (64 granules/row, wave-uniform row,
// XOR-swizzle) and per-thread point groups (thread (g,c) sums pts g*64+j ascending),
// 4-phase merge, ballot counts. part[b][432][456]; update 432-deep ascending.
template<bool FIRST>
__global__ __launch_bounds__(256) void km_assign(const float* __restrict__ x1,
                                                 float* __restrict__ cent,
                                                 float* __restrict__ part) {
    __shared__ float tile[64 * 256];   // 64KB: 64 rows x 64 granules of 4 pts, granule XOR-swizzled by ch
    __shared__ float cs2[64 * 8];
    __shared__ float c2s[8];
    __shared__ int labs[256];
    __shared__ float red[456];
    const int b = blockIdx.y;
    const int q0 = blockIdx.x * 256;   // grid.x = 432
    const int t = threadIdx.x;
    const int c = t & 63, g = t >> 6;

    if (FIRST) {
        for (int idx = t; idx < 448; idx += 256) {
            int k = idx >> 6, ch = idx & 63;
            cs2[ch * 8 + k] = x1[((size_t)b * 64 + ch) * QQ + k];
        }
    } else {
        for (int idx = t; idx < 448; idx += 256) cs2[(idx & 63) * 8 + (idx >> 6)] = cent[b * 448 + idx];
    }
    // async fill (overlaps centroid load): granule gidx holds x1 granule ((gidx&63)^row) of row=gidx>>6
    #pragma unroll
    for (int i = 0; i < 16; i++) {
        const int gidx = t + i * 256;
        const int row = gidx >> 6;              // wave-uniform
        const int c4 = (gidx & 63) ^ row;       // per-lane swizzled source granule
        load16_lds(x1 + ((size_t)b * 64 + row) * QQ + q0 + c4 * 4,
                   (char*)tile + gidx * 16);
    }
    __syncthreads();
    if (t < NK) {
        float s = 0.f;
        for (int ch = 0; ch < 64; ch++) { float v = cs2[ch * 8 + t]; s += v * v; }
        c2s[t] = s;
    }
    if (FIRST && blockIdx.x == 0) {
        for (int idx = t; idx < 448; idx += 256)
            cent[b * 448 + idx] = cs2[(idx & 63) * 8 + (idx >> 6)];
    }
    __syncthreads();

    // assign: thread t -> point t (identical arithmetic to R10)
    float d[NK];
    #pragma unroll
    for (int k = 0; k < NK; k++) d[k] = 0.f;
    for (int ch = 0; ch < 64; ch++) {
        float xv = tile[(ch * 64 + ((t >> 2) ^ ch)) * 4 + (t & 3)];
        float4 ca = *(const float4*)&cs2[ch * 8];
        float4 cb = *(const float4*)&cs2[ch * 8 + 4];
        d[0] += xv * ca.x; d[1] += xv * ca.y; d[2] += xv * ca.z; d[3] += xv * ca.w;
        d[4] += xv * cb.x; d[5] += xv * cb.y; d[6] += xv * cb.z;
    }
    int lab = 0;
    float best = c2s[0] - 2.f * d[0];
    #pragma unroll
    for (int k = 1; k < NK; k++) {
        float dd = c2s[k] - 2.f * d[k];
        if (dd < best) { best = dd; lab = k; }   // strict < => first-min == argmin
    }
    labs[t] = lab;
    __syncthreads();

    float ps[NK], pcnt[NK];
    #pragma unroll
    for (int k = 0; k < NK; k++) { ps[k] = 0.f; pcnt[k] = 0.f; }

    {   // counts: exact integers -> one ballot set per wave
        const int mylb = labs[g * 64 + c];
        #pragma unroll
        for (int k = 0; k < NK; k++)
            pcnt[k] += (float)__popcll(__ballot(mylb == k));
    }

    // sums: float4 reads, 4-element in-order unroll (j ascending), masked adds
    #pragma unroll 4
    for (int j4 = 0; j4 < 16; j4++) {
        const int pt = g * 64 + j4 * 4;
        const int4 lb4 = *(const int4*)&labs[pt];
        const float4 v4 = *(const float4*)&tile[(c * 64 + ((pt >> 2) ^ c)) * 4];
        const int lbs[4] = { lb4.x, lb4.y, lb4.z, lb4.w };
        const float vs[4] = { v4.x, v4.y, v4.z, v4.w };
        #pragma unroll
        for (int u = 0; u < 4; u++) {
            #pragma unroll
            for (int k = 0; k < NK; k++)
                ps[k] += (lbs[u] == k) ? vs[u] : 0.f;
        }
    }

    // 4-phase deterministic merge
    for (int gg = 0; gg < 4; gg++) {
        __syncthreads();
        if (g == gg) {
            if (gg == 0) {
                #pragma unroll
                for (int k = 0; k < NK; k++) red[k * 64 + c] = ps[k];
                if (c == 0) {
                    #pragma unroll
                    for (int k = 0; k < NK; k++) red[448 + k] = pcnt[k];
                }
            } else {
                #pragma unroll
                for (int k = 0; k < NK; k++) red[k * 64 + c] += ps[k];
                if (c == 0) {
                    #pragma unroll
                    for (int k = 0; k < NK; k++) red[448 + k] += pcnt[k];
                }
            }
        }
    }
    __syncthreads();
    float* pb = part + ((size_t)b * 432 + blockIdx.x) * 456;
    for (int idx = t; idx < 455; idx += 256) pb[idx] = red[idx];
}

// grid (2 b, 4 quarters) x 128 thr: 432-deep ascending sums, unroll 16 for load pipelining.
__global__ __launch_bounds__(128) void km_update(const float* __restrict__ part, float* __restrict__ cent) {
    __shared__ float cn_s[8];
    const int b = blockIdx.x, h = blockIdx.y;
    const int t = threadIdx.x;
    const float* pb = part + (size_t)b * 432 * 456;
    if (t < NK) {
        float cn = 0.f;
        #pragma unroll 16
        for (int p = 0; p < 432; p++) cn += pb[p * 456 + 448 + t];
        cn_s[t] = cn;
    }
    __syncthreads();
    int e = h * 112 + t;
    if (t < 112) {
        float s = 0.f;
        #pragma unroll 16
        for (int p = 0; p < 432; p++) s += pb[p * 456 + e];
        float cn = cn_s[e >> 6];
        float oldc = cent[b * 448 + e];
        cent[b * 448 + e] = (cn > 0.f) ? (s / fmaxf(cn, 1.f)) : oldc;
    }
}

// ---------------- centroid MLPs -> WkA (fp16 A-frags), bias2 ----------------
__global__ __launch_bounds__(256) void mlp_kernel(const float* __restrict__ cent,
        const float* __restrict__ kW1, const float* __restrict__ kb1,
        const float* __restrict__ kW2, const float* __restrict__ kb2,
        const float* __restrict__ bW1, const float* __restrict__ bb1,
        const float* __restrict__ bW2, const float* __restrict__ bb2,
        const float* __restrict__ w_mat, uint4* __restrict__ WkA, float* __restrict__ bias2) {
    __shared__ float cr[64];
    __shared__ float hid[256];
    __shared__ float vout[64];
    const int bk = blockIdx.x;
    const int t = threadIdx.x;
    if (t < 64) cr[t] = cent[bk * 64 + t];
    __syncthreads();
    float h = kb1[t];
    for (int c = 0; c < 64; c++) h += cr[c] * kW1[c * 256 + t];
    hid[t] = fmaxf(h, 0.f);
    __syncthreads();
    if (t < 64) {
        float s = kb2[t];
        for (int j = 0; j < 256; j++) s += hid[j] * kW2[j * 64 + t];
        vout[t] = 1.f / (1.f + expf(-s));
    }
    __syncthreads();
    for (int idx = t; idx < 512; idx += 256) {
        int ks = idx >> 7, oh = (idx >> 6) & 1, l = idx & 63;
        int o = oh * 32 + (l & 31);
        U4H8 a;
        #pragma unroll
        for (int j = 0; j < 8; j++) {
            int i = ks * 16 + (l >> 5) * 8 + j;
            a.h[j] = (_Float16)(vout[i] * w_mat[o * 64 + i]);
        }
        WkA[(size_t)bk * 512 + idx] = a.u;
    }
    __syncthreads();
    float h2 = bb1[t];
    for (int c = 0; c < 64; c++) h2 += cr[c] * bW1[c * 256 + t];
    hid[t] = fmaxf(h2, 0.f);
    __syncthreads();
    if (t < 64) {
        float s = bb2[t];
        for (int j = 0; j < 256; j++) s += hid[j] * bW2[j * 64 + t];
        bias2[bk * 64 + t] = s;
    }
}

// ---- scatter_mfma: final assign (from x1) + all-7k MFMA + select + bias/shortcut ----
__global__ __launch_bounds__(256) void scatter_mfma(const float* __restrict__ x1,
        const float* __restrict__ cent,
        const uint4* __restrict__ WkA, const float* __restrict__ bias2, _Float16* __restrict__ oT) {
    __shared__ float tileF[64 * 196];
    __shared__ char tileH[8 * 192 * 16];
    __shared__ float cs2[64 * 8];
    __shared__ float c2s[8];
    __shared__ int labs_s[192];
    __shared__ float bias_s[448];
    const int z = blockIdx.x, ytile = blockIdx.y, b = blockIdx.z;
    const int q0 = z * HWQ + ytile * 192;
    const int t = threadIdx.x, l = t & 63, wv = t >> 6;
    const int oh = wv & 1, qh = wv >> 1;

    for (int idx = t; idx < 64 * 48; idx += 256) {
        int row = idx / 48, c4 = idx % 48;
        float4 v = *(const float4*)(x1 + ((size_t)b * 64 + row) * QQ + q0 + c4 * 4);
        *(float4*)&tileF[row * 196 + c4 * 4] = v;
    }
    for (int idx = t; idx < 448; idx += 256) {
        cs2[(idx & 63) * 8 + (idx >> 6)] = cent[b * 448 + idx];
        bias_s[idx] = bias2[b * 448 + idx];
    }
    __syncthreads();
    for (int idx = t; idx < 1536; idx += 256) {
        int p = idx / 192, q = idx % 192;
        U4H8 pk;
        #pragma unroll
        for (int j = 0; j < 8; j++) pk.h[j] = (_Float16)tileF[(p * 8 + j) * 196 + q];
        *(uint4*)&tileH[(p * 192 + q) * 16] = pk.u;
    }
    if (t < NK) {
        float s = 0.f;
        for (int ch = 0; ch < 64; ch++) { float v = cs2[ch * 8 + t]; s += v * v; }
        c2s[t] = s;
    }
    __syncthreads();
    if (t < 192) {
        float d[NK];
        #pragma unroll
        for (int k = 0; k < NK; k++) d[k] = 0.f;
        for (int ch = 0; ch < 64; ch++) {
            float xv = tileF[ch * 196 + t];
            float4 ca = *(const float4*)&cs2[ch * 8];
            float4 cb = *(const float4*)&cs2[ch * 8 + 4];
            d[0] += xv * ca.x; d[1] += xv * ca.y; d[2] += xv * ca.z; d[3] += xv * ca.w;
            d[4] += xv * cb.x; d[5] += xv * cb.y; d[6] += xv * cb.z;
        }
        int lab = 0;
        float best = c2s[0] - 2.f * d[0];
        #pragma unroll
        for (int k = 1; k < NK; k++) {
            float dd = c2s[k] - 2.f * d[k];
            if (dd < best) { best = dd; lab = k; }
        }
        labs_s[t] = lab;
    }
    __syncthreads();

    int qf[3], la[3];
    #pragma unroll
    for (int f = 0; f < 3; f++) {
        qf[f] = qh * 96 + f * 32 + (l & 31);
        la[f] = labs_s[qf[f]];
    }

    f32x16 outv[3];
    #pragma unroll
    for (int f = 0; f < 3; f++)
        #pragma unroll
        for (int rr = 0; rr < 16; rr++) outv[f][rr] = 0.f;

    for (int k = 0; k < NK; k++) {
        f32x16 acc[3];
        #pragma unroll
        for (int f = 0; f < 3; f++)
            #pragma unroll
            for (int rr = 0; rr < 16; rr++) acc[f][rr] = 0.f;
        const uint4* wp = WkA + (size_t)(b * 7 + k) * 512 + oh * 64 + l;
        #pragma unroll
        for (int ks = 0; ks < 4; ks++) {
            U4H8 a; a.u = wp[ks * 128];
            int p = ks * 2 + (l >> 5);
            #pragma unroll
            for (int f = 0; f < 3; f++) {
                f16x8 bf = *(const f16x8*)&tileH[(p * 192 + qf[f]) * 16];
                acc[f] = __builtin_amdgcn_mfma_f32_32x32x16_f16(a.h, bf, acc[f], 0, 0, 0);
            }
        }
        #pragma unroll
        for (int f = 0; f < 3; f++) outv[f] = (la[f] == k) ? acc[f] : outv[f];
    }

    #pragma unroll
    for (int f = 0; f < 3; f++) {
        int q = qf[f];
        int y = ytile * 4 + q / 48, xx = q % 48;
        #pragma unroll
        for (int rr4 = 0; rr4 < 16; rr4 += 4) {
            int row0 = oh * 32 + 8 * (rr4 >> 2) + 4 * (l >> 5);
            U2H4 pk;
            #pragma unroll
            for (int u = 0; u < 4; u++) {
                int row = row0 + u;
                float val = outv[f][rr4 + u] + bias_s[la[f] * 64 + row] + tileF[row * 196 + q];
                pk.h[u] = (_Float16)val;
            }
            size_t seg = ((((size_t)b * DD + z) * 50 + (y + 1)) * 8 + (row0 >> 3)) * 50 + (xx + 1);
            *(uint2*)((char*)oT + seg * 16 + (row0 & 7) * 2) = pk.u;
        }
    }
}

extern "C" void kernel_launch(void* const* d_in, const int* in_sizes, int n_in,
                              void* d_out, int out_size, void* d_ws, size_t ws_size,
                              hipStream_t stream) {
    const float* x     = (const float*)d_in[0];
    const float* w_in  = (const float*)d_in[1];
    // d_in[2] = b_in : cancelled by InstanceNorm
    const float* w_mat = (const float*)d_in[3];
    const float* kW1   = (const float*)d_in[4];
    const float* kb1   = (const float*)d_in[5];
    const float* kW2   = (const float*)d_in[6];
    const float* kb2   = (const float*)d_in[7];
    const float* bW1   = (const float*)d_in[8];
    const float* bb1   = (const float*)d_in[9];
    const float* bW2   = (const float*)d_in[10];
    const float* bb2   = (const float*)d_in[11];
    const float* w_out = (const float*)d_in[12];
    // d_in[13] = b_out : cancelled by InstanceNorm
    float* out = (float*)d_out;

    char* ws = (char*)d_ws;
    size_t off = 0;
    auto alloc = [&](size_t bytes) { void* p = ws + off; off = (off + bytes + 255) & ~255UL; return p; };
    float*  bufA = (float*)alloc((size_t)2 * 64 * QQ * 4);   // conv1 raw f32; later padded oT fp16
    float*  buf1 = (float*)alloc((size_t)2 * 64 * QQ * 4);   // padded xh+xl fp16; later x1 f32
    char*   bufB = (char*) alloc((size_t)4 << 20);           // part/WkA/bias2/cent
    uint4*  Wp1  = (uint4*)alloc((size_t)27 * 6 * 2 * 64 * 16);
    uint4*  Wp2  = (uint4*)alloc((size_t)27 * 4 * 2 * 64 * 16);
    float2* st   = (float2*)alloc(128 * 8);
    float2* pp   = (float2*)alloc(128 * 8 * 8);
    if (off > ws_size) return;

    _Float16* xh = (_Float16*)buf1;                       // 15.36MB
    _Float16* xl = xh + (size_t)2 * 48 * 50 * 4 * 50 * 8;
    float*    x1 = buf1;                                  // x1 overwrites xh/xl after conv1 (56.6MB)
    _Float16* oT = (_Float16*)bufA;                       // padded oT overwrites raw conv1 out (30.7MB)
    float* part  = (float*)bufB;                          // 2*432*456*4 = 1.58MB
    uint4* WkA   = (uint4*)(bufB + (2u << 20));           // 114KB
    float* bias2 = (float*)(bufB + (2u << 20) + 131072);
    float* cent  = (float*)(bufB + (2u << 20) + 196608);

    transpose_x<<<dim3(10, 48, 2), 256, 0, stream>>>(x, xh, xl);
    prep_w<<<135, 256, 0, stream>>>(w_in, w_out, Wp1, Wp2);

    conv_mfma<96, 32><<<1152, 256, 0, stream>>>(xh, xl, Wp1, bufA);
    stats_part<<<dim3(8, 128), 256, 0, stream>>>(bufA, pp);
    stats_merge<<<1, 128, 0, stream>>>(pp, st);
    inorm_apply<<<dim3(108, 128), 256, 0, stream>>>(bufA, st, x1);       // x1 = normed conv1 (f32)
    zero_borders<<<588, 256, 0, stream>>>((uint4*)oT);                   // halo only (raw bufA dead)

    km_assign<true><<<dim3(432, 2), 256, 0, stream>>>(x1, cent, part);
    km_update<<<dim3(2, 4), 128, 0, stream>>>(part, cent);
    for (int it = 1; it < 8; it++) {
        km_assign<false><<<dim3(432, 2), 256, 0, stream>>>(x1, cent, part);
        km_update<<<dim3(2, 4), 128, 0, stream>>>(part, cent);
    }

    mlp_kernel<<<14, 256, 0, stream>>>(cent, kW1, kb1, kW2, kb2, bW1, bb1, bW2, bb2, w_mat, WkA, bias2);
    scatter_mfma<<<dim3(48, 12, 2), 256, 0, stream>>>(x1, cent, WkA, bias2, oT);

    conv_mfma<64, 64><<<1152, 256, 0, stream>>>(oT, oT, Wp2, out);
    stats_part<<<dim3(8, 128), 256, 0, stream>>>(out, pp);
    stats_merge<<<1, 128, 0, stream>>>(pp, st);
    inorm_apply<<<dim3(108, 128), 256, 0, stream>>>(out, st, out);
}

// Round 14
// 679.342 us; speedup vs baseline: 1.0489x; 1.0489x over previous
//
#include <hip/hip_runtime.h>

#define DD 48
#define HWQ 2304              // 48*48
#define QQ 110592             // 48^3
#define NK 7

typedef _Float16 f16x8 __attribute__((ext_vector_type(8)));
typedef float f32x16 __attribute__((ext_vector_type(16)));
union U4H8 { uint4 u; f16x8 h; };
union U2H4 { uint2 u; _Float16 h[4]; };

__device__ __forceinline__ void load16_lds(const void* g, void* l) {
    __builtin_amdgcn_global_load_lds(
        (const __attribute__((address_space(1))) unsigned int*)g,
        (__attribute__((address_space(3))) unsigned int*)l, 16, 0, 0);
}

// ---- x (f32 [b][32][z][y][x]) -> PADDED hi/lo fp16 [b][z][50y'][4kg][50x'][8ch], zero borders ----
__global__ __launch_bounds__(256) void transpose_x(const float* __restrict__ x,
                                                   _Float16* __restrict__ xh,
                                                   _Float16* __restrict__ xl) {
    const int idx = blockIdx.x * 256 + threadIdx.x;   // 0..2499
    if (idx >= 2500) return;
    const int z = blockIdx.y, b = blockIdx.z;
    const int yp = idx / 50, xp = idx % 50;
    const bool interior = (yp >= 1 && yp <= 48 && xp >= 1 && xp <= 48);
    for (int kg = 0; kg < 4; kg++) {
        U4H8 hi, lo;
        #pragma unroll
        for (int j = 0; j < 8; j++) { hi.h[j] = (_Float16)0.f; lo.h[j] = (_Float16)0.f; }
        if (interior) {
            #pragma unroll
            for (int j = 0; j < 8; j++) {
                float v = x[(((size_t)b * 32 + kg * 8 + j) * DD + z) * HWQ + (yp - 1) * 48 + (xp - 1)];
                _Float16 h = (_Float16)v;
                hi.h[j] = h;
                lo.h[j] = (_Float16)((v - (float)h) * 2048.0f);
            }
        }
        size_t seg = ((((size_t)b * DD + z) * 50 + yp) * 4 + kg) * 50 + xp;
        ((uint4*)xh)[seg] = hi.u;
        ((uint4*)xl)[seg] = lo.u;
    }
}

// ---------------- A-fragment prepack, both convs in one kernel ----------------
__global__ __launch_bounds__(256) void prep_w(const float* __restrict__ w_in,
                                              const float* __restrict__ w_out,
                                              uint4* __restrict__ Wp1, uint4* __restrict__ Wp2) {
    int idx = blockIdx.x * 256 + threadIdx.x;
    const int n1 = 27 * 6 * 2 * 64;   // 20736
    const int n2 = 27 * 4 * 2 * 64;   // 13824
    if (idx < n1) {
        int l = idx & 63; int r = idx >> 6; int oh = r & 1; r >>= 1; int ks = r % 6; int tap = r / 6;
        int o = oh * 32 + (l & 31);
        U4H8 a;
        #pragma unroll
        for (int j = 0; j < 8; j++) {
            int ip = ks * 16 + (l >> 5) * 8 + j;
            _Float16 v;
            if (ip < 32) {
                v = (_Float16)w_in[(o * 32 + ip) * 27 + tap];
            } else if (ip < 64) {
                float w = w_in[(o * 32 + ip - 32) * 27 + tap];
                _Float16 h = (_Float16)w;
                v = (_Float16)((w - (float)h) * 2048.0f);
            } else {
                v = (_Float16)w_in[(o * 32 + ip - 64) * 27 + tap];
            }
            a.h[j] = v;
        }
        Wp1[idx] = a.u;
    } else if (idx < n1 + n2) {
        int j2 = idx - n1;
        int l = j2 & 63; int r = j2 >> 6; int oh = r & 1; r >>= 1; int ks = r % 4; int tap = r / 4;
        int o = oh * 32 + (l & 31);
        U4H8 a;
        #pragma unroll
        for (int j = 0; j < 8; j++) {
            int ip = ks * 16 + (l >> 5) * 8 + j;
            a.h[j] = (_Float16)w_out[(o * 64 + ip) * 27 + tap];
        }
        Wp2[j2] = a.u;
    }
}

// ---- MFMA conv v3 (verified): dz double-buffered staging + XCD-swizzled 1D grid ----
template<int KP, int CINP>
__global__ __launch_bounds__(256) void conv_mfma(const _Float16* __restrict__ src0,
                                                 const _Float16* __restrict__ src1,
                                                 const uint4* __restrict__ Wp,
                                                 float* __restrict__ out) {
    constexpr bool SPLIT = (KP != CINP);       // conv1: 96 vs 32
    constexpr int KSTEPS = KP / 16;
    constexpr int KG = CINP / 8;               // 4 (conv1) or 8 (conv2)
    constexpr int SEGS = 6 * KG * 50;          // per region: 1200 or 2400
    constexpr int YSTRIDE = KG * 800;          // bytes per y' row
    __shared__ char lds[2 * 38400];

    const int lin = blockIdx.x;
    const int swz = (lin & 7) * 144 + (lin >> 3);
    const int b = swz / 576;
    const int rem = swz % 576;
    const int ytile = rem / 48;
    const int z = rem % 48;

    const int tid = threadIdx.x;
    const int l = tid & 63;
    const int wv = tid >> 6;
    const int ohalf = wv & 1, qhalf = wv >> 1;
    const int hi5 = l >> 5;

    int fbase[3];
    #pragma unroll
    for (int f = 0; f < 3; f++) {
        int q = qhalf * 96 + f * 32 + (l & 31);
        fbase[f] = (q / 48) * YSTRIDE + (q % 48) * 16;
    }

    f32x16 accH[3], accL[3];
    #pragma unroll
    for (int f = 0; f < 3; f++)
        #pragma unroll
        for (int rr = 0; rr < 16; rr++) { accH[f][rr] = 0.f; if (SPLIT) accL[f][rr] = 0.f; }

    auto stage = [&](int dz, int bufsel) {
        int zin = z + dz - 1;
        zin = zin < 0 ? 0 : (zin >= DD ? DD - 1 : zin);   // clamp; edge data unused
        const size_t seg0 = (((size_t)b * DD + zin) * 50 + ytile * 4) * (size_t)(KG * 50);
        char* base = lds + bufsel * 38400;
        const _Float16* sA = src0 + seg0 * 8;
        for (int i = tid; i < SEGS; i += 256)
            load16_lds(sA + (size_t)i * 8, base + i * 16);
        if (SPLIT) {
            const _Float16* sB = src1 + seg0 * 8;
            for (int i = tid; i < SEGS; i += 256)
                load16_lds(sB + (size_t)i * 8, base + 19200 + i * 16);
        }
    };

    stage(0, 0);
    __syncthreads();
    for (int dz = 0; dz < 3; dz++) {
        if (dz < 2) stage(dz + 1, (dz + 1) & 1);      // prefetch next plane (other buffer)
        const int zin = z + dz - 1;
        if (zin >= 0 && zin < DD) {
            const char* base = lds + (dz & 1) * 38400;
            for (int dy = 0; dy < 3; dy++) {
                for (int dx = 0; dx < 3; dx++) {
                    const int tap = (dz * 3 + dy) * 3 + dx;
                    const uint4* wp = Wp + ((size_t)(tap * KSTEPS) * 2 + ohalf) * 64 + l;
                    #pragma unroll
                    for (int ks = 0; ks < KSTEPS; ks++) {
                        U4H8 a; a.u = wp[ks * 128];
                        const int kgp = ks * 2;
                        const int pl0 = SPLIT ? ((kgp < CINP / 4) ? (kgp & (CINP / 8 - 1)) : (kgp - CINP / 8))
                                              : kgp;
                        const int plane = pl0 + hi5;
                        const int grp = SPLIT ? (plane >> 2) : 0;
                        const int kg  = SPLIT ? (plane & 3) : plane;
                        const int C = grp * 19200 + kg * 800 + dy * YSTRIDE + dx * 16;
                        #pragma unroll
                        for (int f = 0; f < 3; f++) {
                            f16x8 bf = *(const f16x8*)(base + fbase[f] + C);
                            if constexpr (SPLIT) {
                                if (ks < CINP / 16)
                                    accH[f] = __builtin_amdgcn_mfma_f32_32x32x16_f16(a.h, bf, accH[f], 0, 0, 0);
                                else
                                    accL[f] = __builtin_amdgcn_mfma_f32_32x32x16_f16(a.h, bf, accL[f], 0, 0, 0);
                            } else {
                                accH[f] = __builtin_amdgcn_mfma_f32_32x32x16_f16(a.h, bf, accH[f], 0, 0, 0);
                            }
                        }
                    }
                }
            }
        }
        __syncthreads();
    }

    const size_t obase = (((size_t)b * 64 + ohalf * 32) * DD + z) * HWQ + (size_t)ytile * 192;
    #pragma unroll
    for (int f = 0; f < 3; f++) {
        int q = qhalf * 96 + f * 32 + (l & 31);
        #pragma unroll
        for (int rr = 0; rr < 16; rr++) {
            int row = (rr & 3) + 8 * (rr >> 2) + 4 * (l >> 5);
            float val = accH[f][rr];
            if constexpr (SPLIT) val += accL[f][rr] * (1.0f / 2048.0f);
            out[obase + (size_t)row * QQ + q] = val;
        }
    }
}

// ---------------- InstanceNorm: sliced partial stats + merge ----------------
__global__ __launch_bounds__(256) void stats_part(const float* __restrict__ x, float2* __restrict__ pp) {
    __shared__ float ssum[256], ssq[256];
    const int s = blockIdx.x, bc = blockIdx.y;
    const float4* p = reinterpret_cast<const float4*>(x + (size_t)bc * QQ) + s * (QQ / 32);
    float sm = 0.f, q2 = 0.f;
    for (int i = threadIdx.x; i < QQ / 32; i += 256) {
        float4 v = p[i];
        sm += v.x + v.y + v.z + v.w;
        q2 += v.x * v.x + v.y * v.y + v.z * v.z + v.w * v.w;
    }
    ssum[threadIdx.x] = sm; ssq[threadIdx.x] = q2;
    __syncthreads();
    for (int off = 128; off > 0; off >>= 1) {
        if (threadIdx.x < off) {
            ssum[threadIdx.x] += ssum[threadIdx.x + off];
            ssq[threadIdx.x]  += ssq[threadIdx.x + off];
        }
        __syncthreads();
    }
    if (threadIdx.x == 0) pp[bc * 8 + s] = make_float2(ssum[0], ssq[0]);
}

__global__ __launch_bounds__(128) void stats_merge(const float2* __restrict__ pp, float2* __restrict__ st) {
    int bc = threadIdx.x;
    float sm = 0.f, q2 = 0.f;
    for (int i = 0; i < 8; i++) { float2 v = pp[bc * 8 + i]; sm += v.x; q2 += v.y; }
    float mean = sm / (float)QQ;
    float var = q2 / (float)QQ - mean * mean;
    st[bc] = make_float2(mean, rsqrtf(var + 1e-5f));
}

__global__ __launch_bounds__(256) void inorm_apply(const float* __restrict__ x, const float2* __restrict__ st,
                                                   float* __restrict__ y) {
    const int bc = blockIdx.y;
    float2 mv = st[bc];
    int idx = blockIdx.x * 256 + threadIdx.x;
    float4 v = reinterpret_cast<const float4*>(x + (size_t)bc * QQ)[idx];
    v.x = fmaxf((v.x - mv.x) * mv.y, 0.f);
    v.y = fmaxf((v.y - mv.x) * mv.y, 0.f);
    v.z = fmaxf((v.z - mv.x) * mv.y, 0.f);
    v.w = fmaxf((v.w - mv.x) * mv.y, 0.f);
    reinterpret_cast<float4*>(y + (size_t)bc * QQ)[idx] = v;
}

// ---- zero only the halo segments of padded oT (interior fully written by scatter_mfma) ----
__global__ __launch_bounds__(256) void zero_borders(uint4* __restrict__ oT) {
    int idx = blockIdx.x * 256 + threadIdx.x;
    if (idx >= 2 * 48 * 8 * 196) return;
    int pos = idx % 196; int r = idx / 196;
    int kg = r % 8; r /= 8; int z = r % 48; int b = r / 48;
    int yp, xp;
    if (pos < 50)       { yp = 0;  xp = pos; }
    else if (pos < 100) { yp = 49; xp = pos - 50; }
    else { int e = pos - 100; yp = 1 + (e >> 1); xp = (e & 1) ? 49 : 0; }
    oT[((((size_t)b * 48 + z) * 50 + yp) * 8 + kg) * 50 + xp] = make_uint4(0, 0, 0, 0);
}

// ---------------- k-means: R12 assign (216 x 512-pt) with FUSED centroid update ----------------
// FUSED pass n: recompute cent_n from partP (km_update's exact arithmetic: per-element 216-deep
// ascending sums, counts, s/max(cn,1) with centP fallback) -> cs2 + publish centN; then assign
// exactly as R12; write partials to partN. All blocks compute bit-identical centroids.
template<bool FIRST>
__global__ __launch_bounds__(256) void km_assign(const float* __restrict__ x1,
                                                 const float* __restrict__ centP,
                                                 float* __restrict__ centN,
                                                 const float* __restrict__ partP,
                                                 float* __restrict__ partN) {
    __shared__ float tile[64 * 256];   // 64KB: row ch, 64 granules of 4 pts, granule XOR-swizzled by ch
    __shared__ float cs2[64 * 8];
    __shared__ float c2s[8];
    __shared__ float cn_s[8];
    __shared__ int labs[256];
    __shared__ float red[456];
    const int b = blockIdx.y;
    const int Q0 = blockIdx.x * 512;
    const int t = threadIdx.x;
    const int c = t & 63, g = t >> 6;

    // hoist sub-0 fill: overlaps the centroid work below
    #pragma unroll
    for (int i = 0; i < 16; i++) {
        const int gidx = t + i * 256;
        const int row = gidx >> 6;              // wave-uniform
        const int c4 = (gidx & 63) ^ row;       // per-lane swizzled source granule
        load16_lds(x1 + ((size_t)b * 64 + row) * QQ + Q0 + c4 * 4,
                   (char*)tile + gidx * 16);
    }

    if (FIRST) {
        // deterministic init: centroid k = x1 feature of point q=k; publish to centN
        for (int idx = t; idx < 448; idx += 256) {
            int k = idx >> 6, ch = idx & 63;
            float v = x1[((size_t)b * 64 + ch) * QQ + k];
            cs2[ch * 8 + k] = v;
            centN[b * 448 + idx] = v;
        }
    } else {
        // fused km_update: identical arithmetic to the standalone kernel
        const float* pb = partP + (size_t)b * 216 * 456;
        if (t < NK) {
            float cn = 0.f;
            #pragma unroll 8
            for (int p = 0; p < 216; p++) cn += pb[p * 456 + 448 + t];
            cn_s[t] = cn;
        }
        float s0 = 0.f, s1 = 0.f;
        if (t < 224) {
            const int e0 = t, e1 = t + 224;
            #pragma unroll 8
            for (int p = 0; p < 216; p++) s0 += pb[p * 456 + e0];
            #pragma unroll 8
            for (int p = 0; p < 216; p++) s1 += pb[p * 456 + e1];
        }
        __syncthreads();   // cn_s visible (also drains the sub-0 fill; harmless)
        if (t < 224) {
            const int e0 = t, e1 = t + 224;
            float cn0 = cn_s[e0 >> 6], cn1 = cn_s[e1 >> 6];
            float v0 = (cn0 > 0.f) ? (s0 / fmaxf(cn0, 1.f)) : centP[b * 448 + e0];
            float v1 = (cn1 > 0.f) ? (s1 / fmaxf(cn1, 1.f)) : centP[b * 448 + e1];
            cs2[(e0 & 63) * 8 + (e0 >> 6)] = v0;
            cs2[(e1 & 63) * 8 + (e1 >> 6)] = v1;
            centN[b * 448 + e0] = v0;
            centN[b * 448 + e1] = v1;
        }
    }
    __syncthreads();        // cs2 visible; sub-0 tile drained
    if (t < NK) {
        float s = 0.f;
        for (int ch = 0; ch < 64; ch++) { float v = cs2[ch * 8 + t]; s += v * v; }
        c2s[t] = s;
    }

    float ps[NK], pcnt[NK];
    #pragma unroll
    for (int k = 0; k < NK; k++) { ps[k] = 0.f; pcnt[k] = 0.f; }

    for (int sub = 0; sub < 2; sub++) {
        __syncthreads();   // sub0: c2s visible; sub1: partial reads of tile done
        if (sub == 1) {
            const int q0 = Q0 + 256;
            #pragma unroll
            for (int i = 0; i < 16; i++) {
                const int gidx = t + i * 256;
                const int row = gidx >> 6;
                const int c4 = (gidx & 63) ^ row;
                load16_lds(x1 + ((size_t)b * 64 + row) * QQ + q0 + c4 * 4,
                           (char*)tile + gidx * 16);
            }
            __syncthreads();
        }

        // assign: thread t -> point t (identical arithmetic/order to R12)
        float d[NK];
        #pragma unroll
        for (int k = 0; k < NK; k++) d[k] = 0.f;
        for (int ch = 0; ch < 64; ch++) {
            float xv = tile[(ch * 64 + ((t >> 2) ^ ch)) * 4 + (t & 3)];
            float4 ca = *(const float4*)&cs2[ch * 8];
            float4 cb = *(const float4*)&cs2[ch * 8 + 4];
            d[0] += xv * ca.x; d[1] += xv * ca.y; d[2] += xv * ca.z; d[3] += xv * ca.w;
            d[4] += xv * cb.x; d[5] += xv * cb.y; d[6] += xv * cb.z;
        }
        int lab = 0;
        float best = c2s[0] - 2.f * d[0];
        #pragma unroll
        for (int k = 1; k < NK; k++) {
            float dd = c2s[k] - 2.f * d[k];
            if (dd < best) { best = dd; lab = k; }   // strict < => first-min == argmin
        }
        labs[t] = lab;
        __syncthreads();

        {
            const int mylb = labs[g * 64 + c];
            #pragma unroll
            for (int k = 0; k < NK; k++)
                pcnt[k] += (float)__popcll(__ballot(mylb == k));
        }

        #pragma unroll 4
        for (int j4 = 0; j4 < 16; j4++) {
            const int pt = g * 64 + j4 * 4;
            const int4 lb4 = *(const int4*)&labs[pt];
            const float4 v4 = *(const float4*)&tile[(c * 64 + ((pt >> 2) ^ c)) * 4];
            const int lbs[4] = { lb4.x, lb4.y, lb4.z, lb4.w };
            const float vs[4] = { v4.x, v4.y, v4.z, v4.w };
            #pragma unroll
            for (int u = 0; u < 4; u++) {
                #pragma unroll
                for (int k = 0; k < NK; k++)
                    ps[k] += (lbs[u] == k) ? vs[u] : 0.f;
            }
        }
    }

    // 4-phase deterministic merge (R12 order)
    for (int gg = 0; gg < 4; gg++) {
        __syncthreads();
        if (g == gg) {
            if (gg == 0) {
                #pragma unroll
                for (int k = 0; k < NK; k++) red[k * 64 + c] = ps[k];
                if (c == 0) {
                    #pragma unroll
                    for (int k = 0; k < NK; k++) red[448 + k] = pcnt[k];
                }
            } else {
                #pragma unroll
                for (int k = 0; k < NK; k++) red[k * 64 + c] += ps[k];
                if (c == 0) {
                    #pragma unroll
                    for (int k = 0; k < NK; k++) red[448 + k] += pcnt[k];
                }
            }
        }
    }
    __syncthreads();
    float* pb = partN + ((size_t)b * 216 + blockIdx.x) * 456;
    for (int idx = t; idx < 455; idx += 256) pb[idx] = red[idx];
}

// final centroid update: grid (2 b, 4 quarters) x 128 thr (R12 exact, explicit src/dst)
__global__ __launch_bounds__(128) void km_update(const float* __restrict__ part,
                                                 const float* __restrict__ centP,
                                                 float* __restrict__ centN) {
    __shared__ float cn_s[8];
    const int b = blockIdx.x, h = blockIdx.y;
    const int t = threadIdx.x;
    const float* pb = part + (size_t)b * 216 * 456;
    if (t < NK) {
        float cn = 0.f;
        #pragma unroll 8
        for (int p = 0; p < 216; p++) cn += pb[p * 456 + 448 + t];
        cn_s[t] = cn;
    }
    __syncthreads();
    int e = h * 112 + t;
    if (t < 112) {
        float s = 0.f;
        #pragma unroll 8
        for (int p = 0; p < 216; p++) s += pb[p * 456 + e];
        float cn = cn_s[e >> 6];
        float oldc = centP[b * 448 + e];
        centN[b * 448 + e] = (cn > 0.f) ? (s / fmaxf(cn, 1.f)) : oldc;
    }
}

// ---------------- centroid MLPs -> WkA (fp16 A-frags), bias2 ----------------
__global__ __launch_bounds__(256) void mlp_kernel(const float* __restrict__ cent,
        const float* __restrict__ kW1, const float* __restrict__ kb1,
        const float* __restrict__ kW2, const float* __restrict__ kb2,
        const float* __restrict__ bW1, const float* __restrict__ bb1,
        const float* __restrict__ bW2, const float* __restrict__ bb2,
        const float* __restrict__ w_mat, uint4* __restrict__ WkA, float* __restrict__ bias2) {
    __shared__ float cr[64];
    __shared__ float hid[256];
    __shared__ float vout[64];
    const int bk = blockIdx.x;
    const int t = threadIdx.x;
    if (t < 64) cr[t] = cent[bk * 64 + t];
    __syncthreads();
    float h = kb1[t];
    for (int c = 0; c < 64; c++) h += cr[c] * kW1[c * 256 + t];
    hid[t] = fmaxf(h, 0.f);
    __syncthreads();
    if (t < 64) {
        float s = kb2[t];
        for (int j = 0; j < 256; j++) s += hid[j] * kW2[j * 64 + t];
        vout[t] = 1.f / (1.f + expf(-s));
    }
    __syncthreads();
    for (int idx = t; idx < 512; idx += 256) {
        int ks = idx >> 7, oh = (idx >> 6) & 1, l = idx & 63;
        int o = oh * 32 + (l & 31);
        U4H8 a;
        #pragma unroll
        for (int j = 0; j < 8; j++) {
            int i = ks * 16 + (l >> 5) * 8 + j;
            a.h[j] = (_Float16)(vout[i] * w_mat[o * 64 + i]);
        }
        WkA[(size_t)bk * 512 + idx] = a.u;
    }
    __syncthreads();
    float h2 = bb1[t];
    for (int c = 0; c < 64; c++) h2 += cr[c] * bW1[c * 256 + t];
    hid[t] = fmaxf(h2, 0.f);
    __syncthreads();
    if (t < 64) {
        float s = bb2[t];
        for (int j = 0; j < 256; j++) s += hid[j] * bW2[j * 64 + t];
        bias2[bk * 64 + t] = s;
    }
}

// ---- scatter_mfma: final assign (from x1) + all-7k MFMA + select + bias/shortcut ----
__global__ __launch_bounds__(256) void scatter_mfma(const float* __restrict__ x1,
        const float* __restrict__ cent,
        const uint4* __restrict__ WkA, const float* __restrict__ bias2, _Float16* __restrict__ oT) {
    __shared__ float tileF[64 * 196];
    __shared__ char tileH[8 * 192 * 16];
    __shared__ float cs2[64 * 8];
    __shared__ float c2s[8];
    __shared__ int labs_s[192];
    __shared__ float bias_s[448];
    const int z = blockIdx.x, ytile = blockIdx.y, b = blockIdx.z;
    const int q0 = z * HWQ + ytile * 192;
    const int t = threadIdx.x, l = t & 63, wv = t >> 6;
    const int oh = wv & 1, qh = wv >> 1;

    for (int idx = t; idx < 64 * 48; idx += 256) {
        int row = idx / 48, c4 = idx % 48;
        float4 v = *(const float4*)(x1 + ((size_t)b * 64 + row) * QQ + q0 + c4 * 4);
        *(float4*)&tileF[row * 196 + c4 * 4] = v;
    }
    for (int idx = t; idx < 448; idx += 256) {
        cs2[(idx & 63) * 8 + (idx >> 6)] = cent[b * 448 + idx];
        bias_s[idx] = bias2[b * 448 + idx];
    }
    __syncthreads();
    for (int idx = t; idx < 1536; idx += 256) {
        int p = idx / 192, q = idx % 192;
        U4H8 pk;
        #pragma unroll
        for (int j = 0; j < 8; j++) pk.h[j] = (_Float16)tileF[(p * 8 + j) * 196 + q];
        *(uint4*)&tileH[(p * 192 + q) * 16] = pk.u;
    }
    if (t < NK) {
        float s = 0.f;
        for (int ch = 0; ch < 64; ch++) { float v = cs2[ch * 8 + t]; s += v * v; }
        c2s[t] = s;
    }
    __syncthreads();
    if (t < 192) {
        float d[NK];
        #pragma unroll
        for (int k = 0; k < NK; k++) d[k] = 0.f;
        for (int ch = 0; ch < 64; ch++) {
            float xv = tileF[ch * 196 + t];
            float4 ca = *(const float4*)&cs2[ch * 8];
            float4 cb = *(const float4*)&cs2[ch * 8 + 4];
            d[0] += xv * ca.x; d[1] += xv * ca.y; d[2] += xv * ca.z; d[3] += xv * ca.w;
            d[4] += xv * cb.x; d[5] += xv * cb.y; d[6] += xv * cb.z;
        }
        int lab = 0;
        float best = c2s[0] - 2.f * d[0];
        #pragma unroll
        for (int k = 1; k < NK; k++) {
            float dd = c2s[k] - 2.f * d[k];
            if (dd < best) { best = dd; lab = k; }
        }
        labs_s[t] = lab;
    }
    __syncthreads();

    int qf[3], la[3];
    #pragma unroll
    for (int f = 0; f < 3; f++) {
        qf[f] = qh * 96 + f * 32 + (l & 31);
        la[f] = labs_s[qf[f]];
    }

    f32x16 outv[3];
    #pragma unroll
    for (int f = 0; f < 3; f++)
        #pragma unroll
        for (int rr = 0; rr < 16; rr++) outv[f][rr] = 0.f;

    for (int k = 0; k < NK; k++) {
        f32x16 acc[3];
        #pragma unroll
        for (int f = 0; f < 3; f++)
            #pragma unroll
            for (int rr = 0; rr < 16; rr++) acc[f][rr] = 0.f;
        const uint4* wp = WkA + (size_t)(b * 7 + k) * 512 + oh * 64 + l;
        #pragma unroll
        for (int ks = 0; ks < 4; ks++) {
            U4H8 a; a.u = wp[ks * 128];
            int p = ks * 2 + (l >> 5);
            #pragma unroll
            for (int f = 0; f < 3; f++) {
                f16x8 bf = *(const f16x8*)&tileH[(p * 192 + qf[f]) * 16];
                acc[f] = __builtin_amdgcn_mfma_f32_32x32x16_f16(a.h, bf, acc[f], 0, 0, 0);
            }
        }
        #pragma unroll
        for (int f = 0; f < 3; f++) outv[f] = (la[f] == k) ? acc[f] : outv[f];
    }

    #pragma unroll
    for (int f = 0; f < 3; f++) {
        int q = qf[f];
        int y = ytile * 4 + q / 48, xx = q % 48;
        #pragma unroll
        for (int rr4 = 0; rr4 < 16; rr4 += 4) {
            int row0 = oh * 32 + 8 * (rr4 >> 2) + 4 * (l >> 5);
            U2H4 pk;
            #pragma unroll
            for (int u = 0; u < 4; u++) {
                int row = row0 + u;
                float val = outv[f][rr4 + u] + bias_s[la[f] * 64 + row] + tileF[row * 196 + q];
                pk.h[u] = (_Float16)val;
            }
            size_t seg = ((((size_t)b * DD + z) * 50 + (y + 1)) * 8 + (row0 >> 3)) * 50 + (xx + 1);
            *(uint2*)((char*)oT + seg * 16 + (row0 & 7) * 2) = pk.u;
        }
    }
}

extern "C" void kernel_launch(void* const* d_in, const int* in_sizes, int n_in,
                              void* d_out, int out_size, void* d_ws, size_t ws_size,
                              hipStream_t stream) {
    const float* x     = (const float*)d_in[0];
    const float* w_in  = (const float*)d_in[1];
    // d_in[2] = b_in : cancelled by InstanceNorm
    const float* w_mat = (const float*)d_in[3];
    const float* kW1   = (const float*)d_in[4];
    const float* kb1   = (const float*)d_in[5];
    const float* kW2   = (const float*)d_in[6];
    const float* kb2   = (const float*)d_in[7];
    const float* bW1   = (const float*)d_in[8];
    const float* bb1   = (const float*)d_in[9];
    const float* bW2   = (const float*)d_in[10];
    const float* bb2   = (const float*)d_in[11];
    const float* w_out = (const float*)d_in[12];
    // d_in[13] = b_out : cancelled by InstanceNorm
    float* out = (float*)d_out;

    char* ws = (char*)d_ws;
    size_t off = 0;
    auto alloc = [&](size_t bytes) { void* p = ws + off; off = (off + bytes + 255) & ~255UL; return p; };
    float*  bufA = (float*)alloc((size_t)2 * 64 * QQ * 4);   // conv1 raw f32; later padded oT fp16
    float*  buf1 = (float*)alloc((size_t)2 * 64 * QQ * 4);   // padded xh+xl fp16; later x1 f32
    char*   bufB = (char*) alloc((size_t)4 << 20);           // parts/WkA/bias2/cents
    uint4*  Wp1  = (uint4*)alloc((size_t)27 * 6 * 2 * 64 * 16);
    uint4*  Wp2  = (uint4*)alloc((size_t)27 * 4 * 2 * 64 * 16);
    float2* st   = (float2*)alloc(128 * 8);
    float2* pp   = (float2*)alloc(128 * 8 * 8);
    if (off > ws_size) return;

    _Float16* xh = (_Float16*)buf1;                       // 15.36MB
    _Float16* xl = xh + (size_t)2 * 48 * 50 * 4 * 50 * 8;
    float*    x1 = buf1;                                  // x1 overwrites xh/xl after conv1 (56.6MB)
    _Float16* oT = (_Float16*)bufA;                       // padded oT overwrites raw conv1 out (30.7MB)
    float* partb0 = (float*)bufB;                         // 788KB each
    float* partb1 = (float*)(bufB + (1u << 20));
    uint4* WkA    = (uint4*)(bufB + (2u << 20));          // 114KB
    float* bias2  = (float*)(bufB + (2u << 20) + 131072);
    float* centb0 = (float*)(bufB + (2u << 20) + 196608);
    float* centb1 = (float*)(bufB + (2u << 20) + 204800);
    float* centF  = (float*)(bufB + (2u << 20) + 212992);
    float* partb[2] = { partb0, partb1 };
    float* centb[2] = { centb0, centb1 };

    transpose_x<<<dim3(10, 48, 2), 256, 0, stream>>>(x, xh, xl);
    prep_w<<<135, 256, 0, stream>>>(w_in, w_out, Wp1, Wp2);

    conv_mfma<96, 32><<<1152, 256, 0, stream>>>(xh, xl, Wp1, bufA);
    stats_part<<<dim3(8, 128), 256, 0, stream>>>(bufA, pp);
    stats_merge<<<1, 128, 0, stream>>>(pp, st);
    inorm_apply<<<dim3(108, 128), 256, 0, stream>>>(bufA, st, x1);       // x1 = normed conv1 (f32)
    zero_borders<<<588, 256, 0, stream>>>((uint4*)oT);                   // halo only (raw bufA dead)

    // fused Lloyd: A0 (init) then A1..A7 with in-kernel centroid update; final update -> centF
    km_assign<true><<<dim3(216, 2), 256, 0, stream>>>(x1, nullptr, centb[0], nullptr, partb[0]);
    for (int it = 1; it < 8; it++) {
        km_assign<false><<<dim3(216, 2), 256, 0, stream>>>(
            x1, centb[(it - 1) & 1], centb[it & 1], partb[(it - 1) & 1], partb[it & 1]);
    }
    km_update<<<dim3(2, 4), 128, 0, stream>>>(partb[1], centb[1], centF);   // it=7 wrote partb[1]/centb[1]

    mlp_kernel<<<14, 256, 0, stream>>>(centF, kW1, kb1, kW2, kb2, bW1, bb1, bW2, bb2, w_mat, WkA, bias2);
    scatter_mfma<<<dim3(48, 12, 2), 256, 0, stream>>>(x1, centF, WkA, bias2, oT);

    conv_mfma<64, 64><<<1152, 256, 0, stream>>>(oT, oT, Wp2, out);
    stats_part<<<dim3(8, 128), 256, 0, stream>>>(out, pp);
    stats_merge<<<1, 128, 0, stream>>>(pp, st);
    inorm_apply<<<dim3(108, 128), 256, 0, stream>>>(out, st, out);
}

// Round 16
// 623.776 us; speedup vs baseline: 1.1423x; 1.0891x over previous
//
#include <hip/hip_runtime.h>

#define DD 48
#define HWQ 2304              // 48*48
#define QQ 110592             // 48^3
#define NK 7

typedef _Float16 f16x8 __attribute__((ext_vector_type(8)));
typedef float f32x16 __attribute__((ext_vector_type(16)));
union U4H8 { uint4 u; f16x8 h; };
union U2H4 { uint2 u; _Float16 h[4]; };

__device__ __forceinline__ void load16_lds(const void* g, void* l) {
    __builtin_amdgcn_global_load_lds(
        (const __attribute__((address_space(1))) unsigned int*)g,
        (__attribute__((address_space(3))) unsigned int*)l, 16, 0, 0);
}

// ---- x (f32 [b][32][z][y][x]) -> PADDED hi/lo fp16 [b][z][50y'][4kg][50x'][8ch], zero borders ----
__global__ __launch_bounds__(256) void transpose_x(const float* __restrict__ x,
                                                   _Float16* __restrict__ xh,
                                                   _Float16* __restrict__ xl) {
    const int idx = blockIdx.x * 256 + threadIdx.x;   // 0..2499
    if (idx >= 2500) return;
    const int z = blockIdx.y, b = blockIdx.z;
    const int yp = idx / 50, xp = idx % 50;
    const bool interior = (yp >= 1 && yp <= 48 && xp >= 1 && xp <= 48);
    for (int kg = 0; kg < 4; kg++) {
        U4H8 hi, lo;
        #pragma unroll
        for (int j = 0; j < 8; j++) { hi.h[j] = (_Float16)0.f; lo.h[j] = (_Float16)0.f; }
        if (interior) {
            #pragma unroll
            for (int j = 0; j < 8; j++) {
                float v = x[(((size_t)b * 32 + kg * 8 + j) * DD + z) * HWQ + (yp - 1) * 48 + (xp - 1)];
                _Float16 h = (_Float16)v;
                hi.h[j] = h;
                lo.h[j] = (_Float16)((v - (float)h) * 2048.0f);
            }
        }
        size_t seg = ((((size_t)b * DD + z) * 50 + yp) * 4 + kg) * 50 + xp;
        ((uint4*)xh)[seg] = hi.u;
        ((uint4*)xl)[seg] = lo.u;
    }
}

// ---------------- A-fragment prepack, both convs in one kernel ----------------
__global__ __launch_bounds__(256) void prep_w(const float* __restrict__ w_in,
                                              const float* __restrict__ w_out,
                                              uint4* __restrict__ Wp1, uint4* __restrict__ Wp2) {
    int idx = blockIdx.x * 256 + threadIdx.x;
    const int n1 = 27 * 6 * 2 * 64;   // 20736
    const int n2 = 27 * 4 * 2 * 64;   // 13824
    if (idx < n1) {
        int l = idx & 63; int r = idx >> 6; int oh = r & 1; r >>= 1; int ks = r % 6; int tap = r / 6;
        int o = oh * 32 + (l & 31);
        U4H8 a;
        #pragma unroll
        for (int j = 0; j < 8; j++) {
            int ip = ks * 16 + (l >> 5) * 8 + j;
            _Float16 v;
            if (ip < 32) {
                v = (_Float16)w_in[(o * 32 + ip) * 27 + tap];
            } else if (ip < 64) {
                float w = w_in[(o * 32 + ip - 32) * 27 + tap];
                _Float16 h = (_Float16)w;
                v = (_Float16)((w - (float)h) * 2048.0f);
            } else {
                v = (_Float16)w_in[(o * 32 + ip - 64) * 27 + tap];
            }
            a.h[j] = v;
        }
        Wp1[idx] = a.u;
    } else if (idx < n1 + n2) {
        int j2 = idx - n1;
        int l = j2 & 63; int r = j2 >> 6; int oh = r & 1; r >>= 1; int ks = r % 4; int tap = r / 4;
        int o = oh * 32 + (l & 31);
        U4H8 a;
        #pragma unroll
        for (int j = 0; j < 8; j++) {
            int ip = ks * 16 + (l >> 5) * 8 + j;
            a.h[j] = (_Float16)w_out[(o * 64 + ip) * 27 + tap];
        }
        Wp2[j2] = a.u;
    }
}

// ---- MFMA conv v3 (verified): dz double-buffered staging + XCD-swizzled 1D grid ----
template<int KP, int CINP>
__global__ __launch_bounds__(256) void conv_mfma(const _Float16* __restrict__ src0,
                                                 const _Float16* __restrict__ src1,
                                                 const uint4* __restrict__ Wp,
                                                 float* __restrict__ out) {
    constexpr bool SPLIT = (KP != CINP);       // conv1: 96 vs 32
    constexpr int KSTEPS = KP / 16;
    constexpr int KG = CINP / 8;               // 4 (conv1) or 8 (conv2)
    constexpr int SEGS = 6 * KG * 50;          // per region: 1200 or 2400
    constexpr int YSTRIDE = KG * 800;          // bytes per y' row
    __shared__ char lds[2 * 38400];

    const int lin = blockIdx.x;
    const int swz = (lin & 7) * 144 + (lin >> 3);
    const int b = swz / 576;
    const int rem = swz % 576;
    const int ytile = rem / 48;
    const int z = rem % 48;

    const int tid = threadIdx.x;
    const int l = tid & 63;
    const int wv = tid >> 6;
    const int ohalf = wv & 1, qhalf = wv >> 1;
    const int hi5 = l >> 5;

    int fbase[3];
    #pragma unroll
    for (int f = 0; f < 3; f++) {
        int q = qhalf * 96 + f * 32 + (l & 31);
        fbase[f] = (q / 48) * YSTRIDE + (q % 48) * 16;
    }

    f32x16 accH[3], accL[3];
    #pragma unroll
    for (int f = 0; f < 3; f++)
        #pragma unroll
        for (int rr = 0; rr < 16; rr++) { accH[f][rr] = 0.f; if (SPLIT) accL[f][rr] = 0.f; }

    auto stage = [&](int dz, int bufsel) {
        int zin = z + dz - 1;
        zin = zin < 0 ? 0 : (zin >= DD ? DD - 1 : zin);   // clamp; edge data unused
        const size_t seg0 = (((size_t)b * DD + zin) * 50 + ytile * 4) * (size_t)(KG * 50);
        char* base = lds + bufsel * 38400;
        const _Float16* sA = src0 + seg0 * 8;
        for (int i = tid; i < SEGS; i += 256)
            load16_lds(sA + (size_t)i * 8, base + i * 16);
        if (SPLIT) {
            const _Float16* sB = src1 + seg0 * 8;
            for (int i = tid; i < SEGS; i += 256)
                load16_lds(sB + (size_t)i * 8, base + 19200 + i * 16);
        }
    };

    stage(0, 0);
    __syncthreads();
    for (int dz = 0; dz < 3; dz++) {
        if (dz < 2) stage(dz + 1, (dz + 1) & 1);      // prefetch next plane (other buffer)
        const int zin = z + dz - 1;
        if (zin >= 0 && zin < DD) {
            const char* base = lds + (dz & 1) * 38400;
            for (int dy = 0; dy < 3; dy++) {
                for (int dx = 0; dx < 3; dx++) {
                    const int tap = (dz * 3 + dy) * 3 + dx;
                    const uint4* wp = Wp + ((size_t)(tap * KSTEPS) * 2 + ohalf) * 64 + l;
                    #pragma unroll
                    for (int ks = 0; ks < KSTEPS; ks++) {
                        U4H8 a; a.u = wp[ks * 128];
                        const int kgp = ks * 2;
                        const int pl0 = SPLIT ? ((kgp < CINP / 4) ? (kgp & (CINP / 8 - 1)) : (kgp - CINP / 8))
                                              : kgp;
                        const int plane = pl0 + hi5;
                        const int grp = SPLIT ? (plane >> 2) : 0;
                        const int kg  = SPLIT ? (plane & 3) : plane;
                        const int C = grp * 19200 + kg * 800 + dy * YSTRIDE + dx * 16;
                        #pragma unroll
                        for (int f = 0; f < 3; f++) {
                            f16x8 bf = *(const f16x8*)(base + fbase[f] + C);
                            if constexpr (SPLIT) {
                                if (ks < CINP / 16)
                                    accH[f] = __builtin_amdgcn_mfma_f32_32x32x16_f16(a.h, bf, accH[f], 0, 0, 0);
                                else
                                    accL[f] = __builtin_amdgcn_mfma_f32_32x32x16_f16(a.h, bf, accL[f], 0, 0, 0);
                            } else {
                                accH[f] = __builtin_amdgcn_mfma_f32_32x32x16_f16(a.h, bf, accH[f], 0, 0, 0);
                            }
                        }
                    }
                }
            }
        }
        __syncthreads();
    }

    const size_t obase = (((size_t)b * 64 + ohalf * 32) * DD + z) * HWQ + (size_t)ytile * 192;
    #pragma unroll
    for (int f = 0; f < 3; f++) {
        int q = qhalf * 96 + f * 32 + (l & 31);
        #pragma unroll
        for (int rr = 0; rr < 16; rr++) {
            int row = (rr & 3) + 8 * (rr >> 2) + 4 * (l >> 5);
            float val = accH[f][rr];
            if constexpr (SPLIT) val += accL[f][rr] * (1.0f / 2048.0f);
            out[obase + (size_t)row * QQ + q] = val;
        }
    }
}

// ---------------- InstanceNorm: sliced partial stats + merge ----------------
__global__ __launch_bounds__(256) void stats_part(const float* __restrict__ x, float2* __restrict__ pp) {
    __shared__ float ssum[256], ssq[256];
    const int s = blockIdx.x, bc = blockIdx.y;
    const float4* p = reinterpret_cast<const float4*>(x + (size_t)bc * QQ) + s * (QQ / 32);
    float sm = 0.f, q2 = 0.f;
    for (int i = threadIdx.x; i < QQ / 32; i += 256) {
        float4 v = p[i];
        sm += v.x + v.y + v.z + v.w;
        q2 += v.x * v.x + v.y * v.y + v.z * v.z + v.w * v.w;
    }
    ssum[threadIdx.x] = sm; ssq[threadIdx.x] = q2;
    __syncthreads();
    for (int off = 128; off > 0; off >>= 1) {
        if (threadIdx.x < off) {
            ssum[threadIdx.x] += ssum[threadIdx.x + off];
            ssq[threadIdx.x]  += ssq[threadIdx.x + off];
        }
        __syncthreads();
    }
    if (threadIdx.x == 0) pp[bc * 8 + s] = make_float2(ssum[0], ssq[0]);
}

__global__ __launch_bounds__(128) void stats_merge(const float2* __restrict__ pp, float2* __restrict__ st) {
    int bc = threadIdx.x;
    float sm = 0.f, q2 = 0.f;
    for (int i = 0; i < 8; i++) { float2 v = pp[bc * 8 + i]; sm += v.x; q2 += v.y; }
    float mean = sm / (float)QQ;
    float var = q2 / (float)QQ - mean * mean;
    st[bc] = make_float2(mean, rsqrtf(var + 1e-5f));
}

__global__ __launch_bounds__(256) void inorm_apply(const float* __restrict__ x, const float2* __restrict__ st,
                                                   float* __restrict__ y) {
    const int bc = blockIdx.y;
    float2 mv = st[bc];
    int idx = blockIdx.x * 256 + threadIdx.x;
    float4 v = reinterpret_cast<const float4*>(x + (size_t)bc * QQ)[idx];
    v.x = fmaxf((v.x - mv.x) * mv.y, 0.f);
    v.y = fmaxf((v.y - mv.x) * mv.y, 0.f);
    v.z = fmaxf((v.z - mv.x) * mv.y, 0.f);
    v.w = fmaxf((v.w - mv.x) * mv.y, 0.f);
    reinterpret_cast<float4*>(y + (size_t)bc * QQ)[idx] = v;
}

// ---- zero only the halo segments of padded oT (interior fully written by scatter_mfma) ----
__global__ __launch_bounds__(256) void zero_borders(uint4* __restrict__ oT) {
    int idx = blockIdx.x * 256 + threadIdx.x;
    if (idx >= 2 * 48 * 8 * 196) return;
    int pos = idx % 196; int r = idx / 196;
    int kg = r % 8; r /= 8; int z = r % 48; int b = r / 48;
    int yp, xp;
    if (pos < 50)       { yp = 0;  xp = pos; }
    else if (pos < 100) { yp = 49; xp = pos - 50; }
    else { int e = pos - 100; yp = 1 + (e >> 1); xp = (e & 1) ? 49 : 0; }
    oT[((((size_t)b * 48 + z) * 50 + yp) * 8 + kg) * 50 + xp] = make_uint4(0, 0, 0, 0);
}

// ---------------- k-means on precomputed x1 (f32) — R12 verified ----------------
template<bool FIRST>
__global__ __launch_bounds__(256) void km_assign(const float* __restrict__ x1,
                                                 float* __restrict__ cent,
                                                 float* __restrict__ part) {
    __shared__ float tile[64 * 256];   // 64KB: row ch, 64 granules of 4 pts, granule XOR-swizzled by ch
    __shared__ float cs2[64 * 8];
    __shared__ float c2s[8];
    __shared__ int labs[256];
    __shared__ float red[456];
    const int b = blockIdx.y;
    const int Q0 = blockIdx.x * 512;
    const int t = threadIdx.x;
    const int c = t & 63, g = t >> 6;

    if (FIRST) {
        for (int idx = t; idx < 448; idx += 256) {
            int k = idx >> 6, ch = idx & 63;
            cs2[ch * 8 + k] = x1[((size_t)b * 64 + ch) * QQ + k];
        }
    } else {
        for (int idx = t; idx < 448; idx += 256) cs2[(idx & 63) * 8 + (idx >> 6)] = cent[b * 448 + idx];
    }
    __syncthreads();
    if (t < NK) {
        float s = 0.f;
        for (int ch = 0; ch < 64; ch++) { float v = cs2[ch * 8 + t]; s += v * v; }
        c2s[t] = s;
    }
    if (FIRST && blockIdx.x == 0) {
        for (int idx = t; idx < 448; idx += 256)
            cent[b * 448 + idx] = cs2[(idx & 63) * 8 + (idx >> 6)];
    }

    float ps[NK], pcnt[NK];
    #pragma unroll
    for (int k = 0; k < NK; k++) { ps[k] = 0.f; pcnt[k] = 0.f; }

    for (int sub = 0; sub < 2; sub++) {
        const int q0 = Q0 + sub * 256;
        __syncthreads();
        #pragma unroll
        for (int i = 0; i < 16; i++) {
            const int gidx = t + i * 256;
            const int row = gidx >> 6;              // wave-uniform
            const int c4 = (gidx & 63) ^ row;       // per-lane swizzled source granule
            load16_lds(x1 + ((size_t)b * 64 + row) * QQ + q0 + c4 * 4,
                       (char*)tile + gidx * 16);
        }
        __syncthreads();

        float d[NK];
        #pragma unroll
        for (int k = 0; k < NK; k++) d[k] = 0.f;
        for (int ch = 0; ch < 64; ch++) {
            float xv = tile[(ch * 64 + ((t >> 2) ^ ch)) * 4 + (t & 3)];
            float4 ca = *(const float4*)&cs2[ch * 8];
            float4 cb = *(const float4*)&cs2[ch * 8 + 4];
            d[0] += xv * ca.x; d[1] += xv * ca.y; d[2] += xv * ca.z; d[3] += xv * ca.w;
            d[4] += xv * cb.x; d[5] += xv * cb.y; d[6] += xv * cb.z;
        }
        int lab = 0;
        float best = c2s[0] - 2.f * d[0];
        #pragma unroll
        for (int k = 1; k < NK; k++) {
            float dd = c2s[k] - 2.f * d[k];
            if (dd < best) { best = dd; lab = k; }   // strict < => first-min == argmin
        }
        labs[t] = lab;
        __syncthreads();

        {
            const int mylb = labs[g * 64 + c];
            #pragma unroll
            for (int k = 0; k < NK; k++)
                pcnt[k] += (float)__popcll(__ballot(mylb == k));
        }

        #pragma unroll 4
        for (int j4 = 0; j4 < 16; j4++) {
            const int pt = g * 64 + j4 * 4;
            const int4 lb4 = *(const int4*)&labs[pt];
            const float4 v4 = *(const float4*)&tile[(c * 64 + ((pt >> 2) ^ c)) * 4];
            const int lbs[4] = { lb4.x, lb4.y, lb4.z, lb4.w };
            const float vs[4] = { v4.x, v4.y, v4.z, v4.w };
            #pragma unroll
            for (int u = 0; u < 4; u++) {
                #pragma unroll
                for (int k = 0; k < NK; k++)
                    ps[k] += (lbs[u] == k) ? vs[u] : 0.f;
            }
        }
    }

    for (int gg = 0; gg < 4; gg++) {
        __syncthreads();
        if (g == gg) {
            if (gg == 0) {
                #pragma unroll
                for (int k = 0; k < NK; k++) red[k * 64 + c] = ps[k];
                if (c == 0) {
                    #pragma unroll
                    for (int k = 0; k < NK; k++) red[448 + k] = pcnt[k];
                }
            } else {
                #pragma unroll
                for (int k = 0; k < NK; k++) red[k * 64 + c] += ps[k];
                if (c == 0) {
                    #pragma unroll
                    for (int k = 0; k < NK; k++) red[448 + k] += pcnt[k];
                }
            }
        }
    }
    __syncthreads();
    float* pb = part + ((size_t)b * 216 + blockIdx.x) * 456;
    for (int idx = t; idx < 455; idx += 256) pb[idx] = red[idx];
}

// grid (2 b, 16 slices) x 64 thr: 28 elements/block, per-element 216-deep ascending sum —
// arithmetic identical to R12 (element->block mapping only changes parallelism, not values).
__global__ __launch_bounds__(64) void km_update(const float* __restrict__ part, float* __restrict__ cent) {
    __shared__ float cn_s[8];
    const int b = blockIdx.x, h = blockIdx.y;
    const int t = threadIdx.x;
    const float* pb = part + (size_t)b * 216 * 456;
    if (t < NK) {
        float cn = 0.f;
        #pragma unroll 8
        for (int p = 0; p < 216; p++) cn += pb[p * 456 + 448 + t];
        cn_s[t] = cn;
    }
    __syncthreads();
    int e = h * 28 + t;
    if (t < 28) {
        float s = 0.f;
        #pragma unroll 8
        for (int p = 0; p < 216; p++) s += pb[p * 456 + e];
        float cn = cn_s[e >> 6];
        float oldc = cent[b * 448 + e];
        cent[b * 448 + e] = (cn > 0.f) ? (s / fmaxf(cn, 1.f)) : oldc;
    }
}

// ---------------- centroid MLPs -> WkA (fp16 A-frags), bias2 ----------------
__global__ __launch_bounds__(256) void mlp_kernel(const float* __restrict__ cent,
        const float* __restrict__ kW1, const float* __restrict__ kb1,
        const float* __restrict__ kW2, const float* __restrict__ kb2,
        const float* __restrict__ bW1, const float* __restrict__ bb1,
        const float* __restrict__ bW2, const float* __restrict__ bb2,
        const float* __restrict__ w_mat, uint4* __restrict__ WkA, float* __restrict__ bias2) {
    __shared__ float cr[64];
    __shared__ float hid[256];
    __shared__ float vout[64];
    const int bk = blockIdx.x;
    const int t = threadIdx.x;
    if (t < 64) cr[t] = cent[bk * 64 + t];
    __syncthreads();
    float h = kb1[t];
    for (int c = 0; c < 64; c++) h += cr[c] * kW1[c * 256 + t];
    hid[t] = fmaxf(h, 0.f);
    __syncthreads();
    if (t < 64) {
        float s = kb2[t];
        for (int j = 0; j < 256; j++) s += hid[j] * kW2[j * 64 + t];
        vout[t] = 1.f / (1.f + expf(-s));
    }
    __syncthreads();
    for (int idx = t; idx < 512; idx += 256) {
        int ks = idx >> 7, oh = (idx >> 6) & 1, l = idx & 63;
        int o = oh * 32 + (l & 31);
        U4H8 a;
        #pragma unroll
        for (int j = 0; j < 8; j++) {
            int i = ks * 16 + (l >> 5) * 8 + j;
            a.h[j] = (_Float16)(vout[i] * w_mat[o * 64 + i]);
        }
        WkA[(size_t)bk * 512 + idx] = a.u;
    }
    __syncthreads();
    float h2 = bb1[t];
    for (int c = 0; c < 64; c++) h2 += cr[c] * bW1[c * 256 + t];
    hid[t] = fmaxf(h2, 0.f);
    __syncthreads();
    if (t < 64) {
        float s = bb2[t];
        for (int j = 0; j < 256; j++) s += hid[j] * bW2[j * 64 + t];
        bias2[bk * 64 + t] = s;
    }
}

// ---- scatter_mfma: final assign (from x1) + all-7k MFMA + select + bias/shortcut ----
__global__ __launch_bounds__(256) void scatter_mfma(const float* __restrict__ x1,
        const float* __restrict__ cent,
        const uint4* __restrict__ WkA, const float* __restrict__ bias2, _Float16* __restrict__ oT) {
    __shared__ float tileF[64 * 196];
    __shared__ char tileH[8 * 192 * 16];
    __shared__ float cs2[64 * 8];
    __shared__ float c2s[8];
    __shared__ int labs_s[192];
    __shared__ float bias_s[448];
    const int z = blockIdx.x, ytile = blockIdx.y, b = blockIdx.z;
    const int q0 = z * HWQ + ytile * 192;
    const int t = threadIdx.x, l = t & 63, wv = t >> 6;
    const int oh = wv & 1, qh = wv >> 1;

    for (int idx = t; idx < 64 * 48; idx += 256) {
        int row = idx / 48, c4 = idx % 48;
        float4 v = *(const float4*)(x1 + ((size_t)b * 64 + row) * QQ + q0 + c4 * 4);
        *(float4*)&tileF[row * 196 + c4 * 4] = v;
    }
    for (int idx = t; idx < 448; idx += 256) {
        cs2[(idx & 63) * 8 + (idx >> 6)] = cent[b * 448 + idx];
        bias_s[idx] = bias2[b * 448 + idx];
    }
    __syncthreads();
    for (int idx = t; idx < 1536; idx += 256) {
        int p = idx / 192, q = idx % 192;
        U4H8 pk;
        #pragma unroll
        for (int j = 0; j < 8; j++) pk.h[j] = (_Float16)tileF[(p * 8 + j) * 196 + q];
        *(uint4*)&tileH[(p * 192 + q) * 16] = pk.u;
    }
    if (t < NK) {
        float s = 0.f;
        for (int ch = 0; ch < 64; ch++) { float v = cs2[ch * 8 + t]; s += v * v; }
        c2s[t] = s;
    }
    __syncthreads();
    if (t < 192) {
        float d[NK];
        #pragma unroll
        for (int k = 0; k < NK; k++) d[k] = 0.f;
        for (int ch = 0; ch < 64; ch++) {
            float xv = tileF[ch * 196 + t];
            float4 ca = *(const float4*)&cs2[ch * 8];
            float4 cb = *(const float4*)&cs2[ch * 8 + 4];
            d[0] += xv * ca.x; d[1] += xv * ca.y; d[2] += xv * ca.z; d[3] += xv * ca.w;
            d[4] += xv * cb.x; d[5] += xv * cb.y; d[6] += xv * cb.z;
        }
        int lab = 0;
        float best = c2s[0] - 2.f * d[0];
        #pragma unroll
        for (int k = 1; k < NK; k++) {
            float dd = c2s[k] - 2.f * d[k];
            if (dd < best) { best = dd; lab = k; }
        }
        labs_s[t] = lab;
    }
    __syncthreads();

    int qf[3], la[3];
    #pragma unroll
    for (int f = 0; f < 3; f++) {
        qf[f] = qh * 96 + f * 32 + (l & 31);
        la[f] = labs_s[qf[f]];
    }

    f32x16 outv[3];
    #pragma unroll
    for (int f = 0; f < 3; f++)
        #pragma unroll
        for (int rr = 0; rr < 16; rr++) outv[f][rr] = 0.f;

    for (int k = 0; k < NK; k++) {
        f32x16 acc[3];
        #pragma unroll
        for (int f = 0; f < 3; f++)
            #pragma unroll
            for (int rr = 0; rr < 16; rr++) acc[f][rr] = 0.f;
        const uint4* wp = WkA + (size_t)(b * 7 + k) * 512 + oh * 64 + l;
        #pragma unroll
        for (int ks = 0; ks < 4; ks++) {
            U4H8 a; a.u = wp[ks * 128];
            int p = ks * 2 + (l >> 5);
            #pragma unroll
            for (int f = 0; f < 3; f++) {
                f16x8 bf = *(const f16x8*)&tileH[(p * 192 + qf[f]) * 16];
                acc[f] = __builtin_amdgcn_mfma_f32_32x32x16_f16(a.h, bf, acc[f], 0, 0, 0);
            }
        }
        #pragma unroll
        for (int f = 0; f < 3; f++) outv[f] = (la[f] == k) ? acc[f] : outv[f];
    }

    #pragma unroll
    for (int f = 0; f < 3; f++) {
        int q = qf[f];
        int y = ytile * 4 + q / 48, xx = q % 48;
        #pragma unroll
        for (int rr4 = 0; rr4 < 16; rr4 += 4) {
            int row0 = oh * 32 + 8 * (rr4 >> 2) + 4 * (l >> 5);
            U2H4 pk;
            #pragma unroll
            for (int u = 0; u < 4; u++) {
                int row = row0 + u;
                float val = outv[f][rr4 + u] + bias_s[la[f] * 64 + row] + tileF[row * 196 + q];
                pk.h[u] = (_Float16)val;
            }
            size_t seg = ((((size_t)b * DD + z) * 50 + (y + 1)) * 8 + (row0 >> 3)) * 50 + (xx + 1);
            *(uint2*)((char*)oT + seg * 16 + (row0 & 7) * 2) = pk.u;
        }
    }
}

extern "C" void kernel_launch(void* const* d_in, const int* in_sizes, int n_in,
                              void* d_out, int out_size, void* d_ws, size_t ws_size,
                              hipStream_t stream) {
    const float* x     = (const float*)d_in[0];
    const float* w_in  = (const float*)d_in[1];
    // d_in[2] = b_in : cancelled by InstanceNorm
    const float* w_mat = (const float*)d_in[3];
    const float* kW1   = (const float*)d_in[4];
    const float* kb1   = (const float*)d_in[5];
    const float* kW2   = (const float*)d_in[6];
    const float* kb2   = (const float*)d_in[7];
    const float* bW1   = (const float*)d_in[8];
    const float* bb1   = (const float*)d_in[9];
    const float* bW2   = (const float*)d_in[10];
    const float* bb2   = (const float*)d_in[11];
    const float* w_out = (const float*)d_in[12];
    // d_in[13] = b_out : cancelled by InstanceNorm
    float* out = (float*)d_out;

    char* ws = (char*)d_ws;
    size_t off = 0;
    auto alloc = [&](size_t bytes) { void* p = ws + off; off = (off + bytes + 255) & ~255UL; return p; };
    float*  bufA = (float*)alloc((size_t)2 * 64 * QQ * 4);   // conv1 raw f32; later padded oT fp16
    float*  buf1 = (float*)alloc((size_t)2 * 64 * QQ * 4);   // padded xh+xl fp16; later x1 f32
    char*   bufB = (char*) alloc((size_t)4 << 20);           // part/WkA/bias2/cent
    uint4*  Wp1  = (uint4*)alloc((size_t)27 * 6 * 2 * 64 * 16);
    uint4*  Wp2  = (uint4*)alloc((size_t)27 * 4 * 2 * 64 * 16);
    float2* st   = (float2*)alloc(128 * 8);
    float2* pp   = (float2*)alloc(128 * 8 * 8);
    if (off > ws_size) return;

    _Float16* xh = (_Float16*)buf1;                       // 15.36MB
    _Float16* xl = xh + (size_t)2 * 48 * 50 * 4 * 50 * 8;
    float*    x1 = (float*)buf1;                          // x1 overwrites xh/xl after conv1 (56.6MB)
    _Float16* oT = (_Float16*)bufA;                       // padded oT overwrites raw conv1 out (30.7MB)
    float* part  = (float*)bufB;                          // 2*216*456*4 = 788KB
    uint4* WkA   = (uint4*)(bufB + (1u << 20));           // 114KB
    float* bias2 = (float*)(bufB + (1u << 20) + 131072);
    float* cent  = (float*)(bufB + (1u << 20) + 196608);

    transpose_x<<<dim3(10, 48, 2), 256, 0, stream>>>(x, xh, xl);
    prep_w<<<135, 256, 0, stream>>>(w_in, w_out, Wp1, Wp2);

    conv_mfma<96, 32><<<1152, 256, 0, stream>>>(xh, xl, Wp1, bufA);
    stats_part<<<dim3(8, 128), 256, 0, stream>>>(bufA, pp);
    stats_merge<<<1, 128, 0, stream>>>(pp, st);
    inorm_apply<<<dim3(108, 128), 256, 0, stream>>>(bufA, st, x1);       // x1 = normed conv1 (f32)
    zero_borders<<<588, 256, 0, stream>>>((uint4*)oT);                   // halo only (raw bufA dead)

    km_assign<true><<<dim3(216, 2), 256, 0, stream>>>(x1, cent, part);
    km_update<<<dim3(2, 16), 64, 0, stream>>>(part, cent);
    for (int it = 1; it < 8; it++) {
        km_assign<false><<<dim3(216, 2), 256, 0, stream>>>(x1, cent, part);
        km_update<<<dim3(2, 16), 64, 0, stream>>>(part, cent);
    }

    mlp_kernel<<<14, 256, 0, stream>>>(cent, kW1, kb1, kW2, kb2, bW1, bb1, bW2, bb2, w_mat, WkA, bias2);
    scatter_mfma<<<dim3(48, 12, 2), 256, 0, stream>>>(x1, cent, WkA, bias2, oT);

    conv_mfma<64, 64><<<1152, 256, 0, stream>>>(oT, oT, Wp2, out);
    stats_part<<<dim3(8, 128), 256, 0, stream>>>(out, pp);
    stats_merge<<<1, 128, 0, stream>>>(pp, st);
    inorm_apply<<<dim3(108, 128), 256, 0, stream>>>(out, st, out);
}